// Round 19
// baseline (438.120 us; speedup 1.0000x reference)
//
#include <hip/hip_runtime.h>
#include <hip/hip_bf16.h>
#include <math.h>

typedef _Float16 f16x8 __attribute__((ext_vector_type(8)));
typedef _Float16 f16x4 __attribute__((ext_vector_type(4)));
typedef _Float16 f16x2 __attribute__((ext_vector_type(2)));
typedef float    f32x4 __attribute__((ext_vector_type(4)));
typedef float    f32x2 __attribute__((ext_vector_type(2)));

#define DIMD    256
#define MT      64          // rows per block
#define BT      256         // 4 waves; each wave owns 16 rows x 256 cols
#define KSTEPS  26
#define LOG2E   1.4426950408889634f   // le5 = mask*LOG2E = log2(E)/5 (no max-sub)
#define INV_1MP 1.1111111111111112f   // 1/(1-P), P=0.1

static __device__ __forceinline__ f16x2 cvt_pk(float a, float b) {
    return __builtin_bit_cast(f16x2, __builtin_amdgcn_cvt_pkrtz(a, b));
}

// ---- packed-f32 VALU helpers (VOP3P) -------------------------------------
static __device__ __forceinline__ f32x2 pk_fma(f32x2 a, f32x2 b, f32x2 c) {
    f32x2 d;
    asm("v_pk_fma_f32 %0, %1, %2, %3" : "=v"(d) : "v"(a), "v"(b), "v"(c));
    return d;
}
static __device__ __forceinline__ f32x2 pk_mul(f32x2 a, f32x2 b) {
    f32x2 d;
    asm("v_pk_mul_f32 %0, %1, %2" : "=v"(d) : "v"(a), "v"(b));
    return d;
}
static __device__ __forceinline__ f32x2 pk_add(f32x2 a, f32x2 b) {
    f32x2 d;
    asm("v_pk_add_f32 %0, %1, %2" : "=v"(d) : "v"(a), "v"(b));
    return d;
}

// ---- DPP row_ror cross-lane (16-lane groups) -----------------------------
template<int CTRL>
static __device__ __forceinline__ float dpp_ror(float s) {
    return __builtin_bit_cast(float, __builtin_amdgcn_update_dpp(
        0, __builtin_bit_cast(int, s), CTRL, 0xf, 0xf, false));
}
static __device__ __forceinline__ float row16_sum(float s) {
    s += dpp_ror<0x128>(s);
    s += dpp_ror<0x124>(s);
    s += dpp_ror<0x122>(s);
    s += dpp_ror<0x121>(s);
    return s;
}

// ---- pre-kernel: W[c][k] fp32 -> frag-major fp16 -------------------------
__global__ __launch_bounds__(256)
void w_conv_kernel(const float* __restrict__ W, f16x8* __restrict__ ws) {
    int gid  = blockIdx.x * 256 + threadIdx.x;
    int tile = gid >> 6;
    int lane = gid & 63;
    int kt = tile >> 4, ct = tile & 15;
    int col = ct * 16 + (lane & 15);
    int k0  = kt * 32 + (lane >> 4) * 8;
    const float* wr = W + col * 256 + k0;
    float4 f01 = *(const float4*)wr;
    float4 f23 = *(const float4*)(wr + 4);
    float wv[8] = {f01.x, f01.y, f01.z, f01.w, f23.x, f23.y, f23.z, f23.w};
    f16x8 hi;
    #pragma unroll
    for (int j = 0; j < 8; ++j) hi[j] = (_Float16)wv[j];
    ws[tile * 64 + lane] = hi;
}

// GEMM over one 64-col chunk (ct = 4C..4C+3): acc only 16 regs, compressed
// immediately to fp16 le5. le[C][p][i] covers cc = 2C+i (cols (2cc|h)*16+..).
#define GEMM_CHUNK(C)                                                         \
{                                                                             \
    f32x4 acc[4];                                                             \
    _Pragma("unroll")                                                         \
    for (int t = 0; t < 4; ++t) {                                             \
        float b = bias[(4 * (C) + t) * 16 + (lane & 15)];                     \
        acc[t] = f32x4{b, b, b, b};                                           \
    }                                                                         \
    _Pragma("unroll")                                                         \
    for (int kt = 0; kt < 8; ++kt) {                                          \
        int kbyte = kt * 64 + kgrp;                                           \
        f16x8 a8 = *(const f16x8*)(smem + abase + (kbyte ^ swzA));            \
        _Pragma("unroll")                                                     \
        for (int t = 0; t < 4; ++t) {                                         \
            f16x8 bh = ws[(kt * 16 + 4 * (C) + t) * 64 + lane];               \
            acc[t] = __builtin_amdgcn_mfma_f32_16x16x32_f16(a8, bh,           \
                                                            acc[t], 0, 0, 0); \
        }                                                                     \
    }                                                                         \
    _Pragma("unroll")                                                         \
    for (int p = 0; p < 4; ++p) {                                             \
        le[C][p][0] = cvt_pk(acc[0][p] * LOG2E, acc[1][p] * LOG2E);           \
        le[C][p][1] = cvt_pk(acc[2][p] * LOG2E, acc[3][p] * LOG2E);           \
        asm volatile("" : "+v"(le[C][p][0]), "+v"(le[C][p][1]));              \
    }                                                                         \
}

// ---- main fused kernel ----------------------------------------------------
// LDS: A fp16 [64 rows][256 cols], 32 KB; byte-XOR swizzle:
//   byte = row*512 + ((col*2) ^ ((row&7)<<4))
__global__ __launch_bounds__(BT, 4)
void sad_mfma_kernel(const float* __restrict__ feat,
                     const float* __restrict__ bias,
                     const f16x8* __restrict__ ws,
                     float* __restrict__ out,
                     int N)
{
    __shared__ __align__(16) unsigned char smem[MT * 512];  // 32 KB

    const int tid  = threadIdx.x;
    const int lane = tid & 63;
    const int wv   = tid >> 6;           // wave 0..3, owns rows wv*16..+15
    const long long n0 = (long long)blockIdx.x * MT;

    // ---- stage 64 feature rows -> fp16 LDS (swizzled) ----
    const float4* fvec = (const float4*)feat;
    #pragma unroll
    for (int i = 0; i < 16; ++i) {
        int flat4 = i * BT + tid;
        int row = flat4 >> 6;
        int c4  = flat4 & 63;
        long long grow = n0 + row;
        if (grow >= N) grow = N - 1;
        float4 f = fvec[grow * 64 + c4];
        f16x4 h4;
        h4[0] = (_Float16)f.x; h4[1] = (_Float16)f.y;
        h4[2] = (_Float16)f.z; h4[3] = (_Float16)f.w;
        int off = row * 512 + ((c4 * 8) ^ ((row & 7) << 4));
        *(f16x4*)(smem + off) = h4;
    }
    __syncthreads();

    const int arow  = wv * 16 + (lane & 15);
    const int swzA  = (arow & 7) << 4;
    const int abase = arow * 512;
    const int kgrp  = (lane >> 4) * 16;

    // ---- GEMM in 4 col-chunks; acc never exceeds 16 regs ----
    f16x2 le[4][4][2];   // [chunk][plane][pair] -- all static indexing
    GEMM_CHUNK(0)
    asm volatile("" ::: "memory");
    GEMM_CHUNK(1)
    asm volatile("" ::: "memory");
    GEMM_CHUNK(2)
    asm volatile("" ::: "memory");
    GEMM_CHUNK(3)
    asm volatile("" ::: "memory");

    const f32x2 one2 = f32x2{1.0f, 1.0f};

    // ---- quad-interleaved peel: 4 planes' chains in flight ---------------
    // q[p][cc] pairs with le[cc>>1][p][cc&1]; all indices static after unroll.
    f32x2 q[4][8];
    #pragma unroll
    for (int p = 0; p < 4; ++p) {
        #pragma unroll
        for (int cc = 0; cc < 8; ++cc) {
            q[p][cc] = f32x2{
                __builtin_amdgcn_exp2f(5.0f * (float)le[cc >> 1][p][cc & 1][0]),
                __builtin_amdgcn_exp2f(5.0f * (float)le[cc >> 1][p][cc & 1][1])};
        }
    }

    #pragma unroll 1
    for (int it = 0; it < KSTEPS; ++it) {
        f32x2 nrv[4];
        #pragma unroll
        for (int p = 0; p < 4; ++p) {
            f32x2 s2 = pk_add(
                pk_add(pk_add(q[p][0], q[p][1]), pk_add(q[p][2], q[p][3])),
                pk_add(pk_add(q[p][4], q[p][5]), pk_add(q[p][6], q[p][7])));
            float s = row16_sum(s2.x + s2.y);
            s = fmaxf(s, 1e-30f);
            float nr = -__builtin_amdgcn_rcpf(s);
            nrv[p] = f32x2{nr, nr};
        }
        #pragma unroll
        for (int cc = 0; cc < 8; ++cc) {
            #pragma unroll
            for (int p = 0; p < 4; ++p) {
                f32x2 r  = pk_fma(q[p][cc], nrv[p], one2);  // 1 - q/S
                f32x2 r2 = pk_mul(r, r);
                f32x2 r4 = pk_mul(r2, r2);
                f32x2 r5 = pk_mul(r4, r);
                q[p][cc] = pk_mul(q[p][cc], r5);            // q *= r^5
            }
        }
    }

    // ---- epilogue: z = exp2(0.2*log2(q) - le5); out = f*z/(1-P) ----------
    #pragma unroll
    for (int p = 0; p < 4; ++p) {
        int row = wv * 16 + (lane >> 4) * 4 + p;
        long long grow = n0 + row;
        if (grow < N) {
            int swz = (row & 7) << 4;
            float* orow = out + grow * 256;
            #pragma unroll
            for (int cc = 0; cc < 8; ++cc) {
                #pragma unroll
                for (int h = 0; h < 2; ++h) {
                    int col = (2 * cc + h) * 16 + (lane & 15);
                    float le5 = (float)le[cc >> 1][p][cc & 1][h];
                    float qv  = fmaxf(h ? q[p][cc].y : q[p][cc].x, 1e-38f);
                    float zz  = __builtin_amdgcn_exp2f(
                        fmaf(__builtin_amdgcn_logf(qv), 0.2f, -le5));
                    int off = row * 512 + ((col * 2) ^ swz);
                    float fval = (float)(*(const _Float16*)(smem + off));
                    orow[col] = fval * (zz * INV_1MP);
                }
            }
        }
    }
}

extern "C" void kernel_launch(void* const* d_in, const int* in_sizes, int n_in,
                              void* d_out, int out_size, void* d_ws, size_t ws_size,
                              hipStream_t stream) {
    const float* feat = (const float*)d_in[0];
    const float* W    = (const float*)d_in[1];
    const float* bias = (const float*)d_in[2];
    float* out = (float*)d_out;
    int N = in_sizes[0] / DIMD;

    // 1) W -> frag-major fp16 in workspace (128 KB)
    w_conv_kernel<<<32, 256, 0, stream>>>(W, (f16x8*)d_ws);

    // 2) fused chunked-GEMM + quad-interleaved q-form peeling
    int grid = (N + MT - 1) / MT;
    sad_mfma_kernel<<<grid, BT, 0, stream>>>(feat, bias, (const f16x8*)d_ws, out, N);
}

// Round 20
// 317.067 us; speedup vs baseline: 1.3818x; 1.3818x over previous
//
#include <hip/hip_runtime.h>
#include <hip/hip_bf16.h>
#include <math.h>

typedef _Float16 f16x8 __attribute__((ext_vector_type(8)));
typedef _Float16 f16x4 __attribute__((ext_vector_type(4)));
typedef _Float16 f16x2 __attribute__((ext_vector_type(2)));
typedef float    f32x4 __attribute__((ext_vector_type(4)));
typedef float    f32x2 __attribute__((ext_vector_type(2)));

#define DIMD    256
#define MT      64          // rows per block
#define BT      256         // 4 waves; each wave owns 16 rows x 256 cols
#define KSTEPS  26
#define LOG2E   1.4426950408889634f   // le5 = mask*LOG2E = log2(E)/5 (no max-sub)
#define INV_1MP 1.1111111111111112f   // 1/(1-P), P=0.1

static __device__ __forceinline__ f16x2 cvt_pk(float a, float b) {
    return __builtin_bit_cast(f16x2, __builtin_amdgcn_cvt_pkrtz(a, b));
}

// ---- packed-f32 VALU helpers (VOP3P) -------------------------------------
static __device__ __forceinline__ f32x2 pk_fma(f32x2 a, f32x2 b, f32x2 c) {
    f32x2 d;
    asm("v_pk_fma_f32 %0, %1, %2, %3" : "=v"(d) : "v"(a), "v"(b), "v"(c));
    return d;
}
static __device__ __forceinline__ f32x2 pk_mul(f32x2 a, f32x2 b) {
    f32x2 d;
    asm("v_pk_mul_f32 %0, %1, %2" : "=v"(d) : "v"(a), "v"(b));
    return d;
}
static __device__ __forceinline__ f32x2 pk_add(f32x2 a, f32x2 b) {
    f32x2 d;
    asm("v_pk_add_f32 %0, %1, %2" : "=v"(d) : "v"(a), "v"(b));
    return d;
}

// ---- DPP row_ror cross-lane (16-lane groups) -----------------------------
template<int CTRL>
static __device__ __forceinline__ float dpp_ror(float s) {
    return __builtin_bit_cast(float, __builtin_amdgcn_update_dpp(
        0, __builtin_bit_cast(int, s), CTRL, 0xf, 0xf, false));
}
static __device__ __forceinline__ float row16_sum(float s) {
    s += dpp_ror<0x128>(s);
    s += dpp_ror<0x124>(s);
    s += dpp_ror<0x122>(s);
    s += dpp_ror<0x121>(s);
    return s;
}

// ---- pre-kernel: W[c][k] fp32 -> frag-major fp16 -------------------------
__global__ __launch_bounds__(256)
void w_conv_kernel(const float* __restrict__ W, f16x8* __restrict__ ws) {
    int gid  = blockIdx.x * 256 + threadIdx.x;
    int tile = gid >> 6;
    int lane = gid & 63;
    int kt = tile >> 4, ct = tile & 15;
    int col = ct * 16 + (lane & 15);
    int k0  = kt * 32 + (lane >> 4) * 8;
    const float* wr = W + col * 256 + k0;
    float4 f01 = *(const float4*)wr;
    float4 f23 = *(const float4*)(wr + 4);
    float wv[8] = {f01.x, f01.y, f01.z, f01.w, f23.x, f23.y, f23.z, f23.w};
    f16x8 hi;
    #pragma unroll
    for (int j = 0; j < 8; ++j) hi[j] = (_Float16)wv[j];
    ws[tile * 64 + lane] = hi;
}

// GEMM over one 64-col chunk (ct = 4C..4C+3): acc only 16 regs, compressed
// immediately to fp16 le5 (no row max: |mask| bounded so exp2 stays in f32).
#define GEMM_CHUNK(C, LE)                                                     \
{                                                                             \
    f32x4 acc[4];                                                             \
    _Pragma("unroll")                                                         \
    for (int t = 0; t < 4; ++t) {                                             \
        float b = bias[(4 * (C) + t) * 16 + (lane & 15)];                     \
        acc[t] = f32x4{b, b, b, b};                                           \
    }                                                                         \
    _Pragma("unroll")                                                         \
    for (int kt = 0; kt < 8; ++kt) {                                          \
        int kbyte = kt * 64 + kgrp;                                           \
        f16x8 a8 = *(const f16x8*)(smem + abase + (kbyte ^ swzA));            \
        _Pragma("unroll")                                                     \
        for (int t = 0; t < 4; ++t) {                                         \
            f16x8 bh = ws[(kt * 16 + 4 * (C) + t) * 64 + lane];               \
            acc[t] = __builtin_amdgcn_mfma_f32_16x16x32_f16(a8, bh,           \
                                                            acc[t], 0, 0, 0); \
        }                                                                     \
    }                                                                         \
    _Pragma("unroll")                                                         \
    for (int p = 0; p < 4; ++p) {                                             \
        LE[p][0] = cvt_pk(acc[0][p] * LOG2E, acc[1][p] * LOG2E);              \
        LE[p][1] = cvt_pk(acc[2][p] * LOG2E, acc[3][p] * LOG2E);              \
        asm volatile("" : "+v"(LE[p][0]), "+v"(LE[p][1]));                    \
    }                                                                         \
}

// Static epilogue for one plane (no pointer selects -- rule #20 safe).
#define EPILOGUE(P, LP, Q)                                                    \
{                                                                             \
    int row = wv * 16 + (lane >> 4) * 4 + (P);                                \
    long long grow = n0 + row;                                                \
    if (grow < N) {                                                           \
        int swz = (row & 7) << 4;                                             \
        float* orow = out + grow * 256;                                       \
        _Pragma("unroll")                                                     \
        for (int cc = 0; cc < 8; ++cc) {                                      \
            _Pragma("unroll")                                                 \
            for (int h = 0; h < 2; ++h) {                                     \
                int col = (2 * cc + h) * 16 + (lane & 15);                    \
                float le5 = (float)LP[cc][h];                                 \
                float qv  = fmaxf(h ? Q[cc].y : Q[cc].x, 1e-38f);             \
                float zz  = __builtin_amdgcn_exp2f(                           \
                    fmaf(__builtin_amdgcn_logf(qv), 0.2f, -le5));             \
                int off = row * 512 + ((col * 2) ^ swz);                      \
                float fval = (float)(*(const _Float16*)(smem + off));         \
                orow[col] = fval * (zz * INV_1MP);                            \
            }                                                                 \
        }                                                                     \
    }                                                                         \
}

// Two planes interleaved: two independent sum->DPP->rcp->update chains so
// one plane's serial reduce latency hides under the other's update issue.
#define PEEL_PAIR(P0, P1)                                                     \
{                                                                             \
    f16x2 lpa[8] = {le0[P0][0], le0[P0][1], le1[P0][0], le1[P0][1],           \
                    le2[P0][0], le2[P0][1], le3[P0][0], le3[P0][1]};          \
    f16x2 lpb[8] = {le0[P1][0], le0[P1][1], le1[P1][0], le1[P1][1],           \
                    le2[P1][0], le2[P1][1], le3[P1][0], le3[P1][1]};          \
    f32x2 qa[8], qb[8];                                                       \
    _Pragma("unroll")                                                         \
    for (int cc = 0; cc < 8; ++cc) {                                          \
        qa[cc] = f32x2{__builtin_amdgcn_exp2f(5.0f * (float)lpa[cc][0]),      \
                       __builtin_amdgcn_exp2f(5.0f * (float)lpa[cc][1])};     \
        qb[cc] = f32x2{__builtin_amdgcn_exp2f(5.0f * (float)lpb[cc][0]),      \
                       __builtin_amdgcn_exp2f(5.0f * (float)lpb[cc][1])};     \
    }                                                                         \
    _Pragma("unroll 1")                                                       \
    for (int it = 0; it < KSTEPS; ++it) {                                     \
        f32x2 sa2 = pk_add(pk_add(pk_add(qa[0], qa[1]), pk_add(qa[2], qa[3])),\
                           pk_add(pk_add(qa[4], qa[5]), pk_add(qa[6], qa[7])));\
        f32x2 sb2 = pk_add(pk_add(pk_add(qb[0], qb[1]), pk_add(qb[2], qb[3])),\
                           pk_add(pk_add(qb[4], qb[5]), pk_add(qb[6], qb[7])));\
        float sa = row16_sum(sa2.x + sa2.y);                                  \
        float sb = row16_sum(sb2.x + sb2.y);                                  \
        sa = fmaxf(sa, 1e-30f);                                               \
        sb = fmaxf(sb, 1e-30f);                                               \
        float na = -__builtin_amdgcn_rcpf(sa);                                \
        float nb = -__builtin_amdgcn_rcpf(sb);                                \
        f32x2 nva = f32x2{na, na};                                            \
        f32x2 nvb = f32x2{nb, nb};                                            \
        _Pragma("unroll")                                                     \
        for (int cc = 0; cc < 8; ++cc) {                                      \
            f32x2 ra  = pk_fma(qa[cc], nva, one2);                            \
            f32x2 rb  = pk_fma(qb[cc], nvb, one2);                            \
            f32x2 ra2 = pk_mul(ra, ra);                                       \
            f32x2 rb2 = pk_mul(rb, rb);                                       \
            f32x2 ra4 = pk_mul(ra2, ra2);                                     \
            f32x2 rb4 = pk_mul(rb2, rb2);                                     \
            f32x2 ra5 = pk_mul(ra4, ra);                                      \
            f32x2 rb5 = pk_mul(rb4, rb);                                      \
            qa[cc] = pk_mul(qa[cc], ra5);                                     \
            qb[cc] = pk_mul(qb[cc], rb5);                                     \
        }                                                                     \
    }                                                                         \
    EPILOGUE(P0, lpa, qa)                                                     \
    EPILOGUE(P1, lpb, qb)                                                     \
}                                                                             \
asm volatile("" ::: "memory");

// ---- main fused kernel ----------------------------------------------------
// LDS: A fp16 [64 rows][256 cols], 32 KB; byte-XOR swizzle:
//   byte = row*512 + ((col*2) ^ ((row&7)<<4))
__global__ __launch_bounds__(BT, 4)
void sad_mfma_kernel(const float* __restrict__ feat,
                     const float* __restrict__ bias,
                     const f16x8* __restrict__ ws,
                     float* __restrict__ out,
                     int N)
{
    __shared__ __align__(16) unsigned char smem[MT * 512];  // 32 KB

    const int tid  = threadIdx.x;
    const int lane = tid & 63;
    const int wv   = tid >> 6;           // wave 0..3, owns rows wv*16..+15
    const long long n0 = (long long)blockIdx.x * MT;

    // ---- stage 64 feature rows -> fp16 LDS (swizzled) ----
    const float4* fvec = (const float4*)feat;
    #pragma unroll
    for (int i = 0; i < 16; ++i) {
        int flat4 = i * BT + tid;
        int row = flat4 >> 6;
        int c4  = flat4 & 63;
        long long grow = n0 + row;
        if (grow >= N) grow = N - 1;
        float4 f = fvec[grow * 64 + c4];
        f16x4 h4;
        h4[0] = (_Float16)f.x; h4[1] = (_Float16)f.y;
        h4[2] = (_Float16)f.z; h4[3] = (_Float16)f.w;
        int off = row * 512 + ((c4 * 8) ^ ((row & 7) << 4));
        *(f16x4*)(smem + off) = h4;
    }
    __syncthreads();

    const int arow  = wv * 16 + (lane & 15);
    const int swzA  = (arow & 7) << 4;
    const int abase = arow * 512;
    const int kgrp  = (lane >> 4) * 16;

    // ---- GEMM in 4 col-chunks; acc never exceeds 16 regs ----
    f16x2 le0[4][2], le1[4][2], le2[4][2], le3[4][2];
    GEMM_CHUNK(0, le0)
    asm volatile("" ::: "memory");
    GEMM_CHUNK(1, le1)
    asm volatile("" ::: "memory");
    GEMM_CHUNK(2, le2)
    asm volatile("" ::: "memory");
    GEMM_CHUNK(3, le3)
    asm volatile("" ::: "memory");

    const f32x2 one2 = f32x2{1.0f, 1.0f};

    // ---- two pair-interleaved peels (q-form, pk-f32, dual chains) --------
    PEEL_PAIR(0, 1)
    PEEL_PAIR(2, 3)
}

extern "C" void kernel_launch(void* const* d_in, const int* in_sizes, int n_in,
                              void* d_out, int out_size, void* d_ws, size_t ws_size,
                              hipStream_t stream) {
    const float* feat = (const float*)d_in[0];
    const float* W    = (const float*)d_in[1];
    const float* bias = (const float*)d_in[2];
    float* out = (float*)d_out;
    int N = in_sizes[0] / DIMD;

    // 1) W -> frag-major fp16 in workspace (128 KB)
    w_conv_kernel<<<32, 256, 0, stream>>>(W, (f16x8*)d_ws);

    // 2) fused chunked-GEMM + pair-interleaved q-form peeling
    int grid = (N + MT - 1) / MT;
    sad_mfma_kernel<<<grid, BT, 0, stream>>>(feat, bias, (const f16x8*)d_ws, out, N);
}